// Round 1
// 164.369 us; speedup vs baseline: 1.0425x; 1.0425x over previous
//
#include <hip/hip_runtime.h>
#include <hip/hip_bf16.h>

#define HW   4096
#define HW4  1024
#define EPS  1e-5f
#define SM_SHIFT 20.0f   // constant-shift softmax: exp(s - SM_SHIFT); |s| << 20 by construction

typedef __attribute__((ext_vector_type(8))) short bf16x8;   // 8 bf16 (4 VGPRs)
typedef __attribute__((ext_vector_type(4))) float f32x4;    // MFMA C/D

__device__ __forceinline__ short f2bs(float f) {            // fp32 -> bf16 bits (RNE)
    union { float f; unsigned u; } v; v.f = f;
    unsigned r = v.u + 0x7FFFu + ((v.u >> 16) & 1u);
    return (short)(r >> 16);
}
// XOR-swizzled LDS layouts (16B chunks permuted by row), row strides 64/128 shorts.
__device__ __forceinline__ int swz64(int r, int c)  { return (r << 6) + ((c ^ (r & 7))  << 3); }
__device__ __forceinline__ int swz128(int r, int c) { return (r << 7) + ((c ^ (r & 15)) << 3); }
// Padded 40-short (80B) rows: bank base = 20*r mod 32 -> full bank spread for 32-k rows.
__device__ __forceinline__ int p40(int r, int c)    { return r * 40 + c * 8; }

// ---------------------------------------------------------------------------
// Kernel 1: conv1x1+BN+ReLU branches 1-3, 2x2 maxpool fused in registers.
// Grid (32 ptile, 2 ocg, 8 bz) = 512 blocks -> 2 blocks/CU.
// NEW: f written transposed (fbufT[n][k]) so kernel2 can load s-phase
// fragments directly from global, coalesced. w4 converted to bf16 once here.
// ---------------------------------------------------------------------------
__global__ __launch_bounds__(256) void conv123pool(
    const float* __restrict__ x,
    const float* __restrict__ w1, const float* __restrict__ b1, const float* __restrict__ s1,
    const float* __restrict__ t1, const float* __restrict__ m1, const float* __restrict__ v1,
    const float* __restrict__ w2, const float* __restrict__ b2, const float* __restrict__ s2,
    const float* __restrict__ t2, const float* __restrict__ m2, const float* __restrict__ v2,
    const float* __restrict__ w3, const float* __restrict__ b3, const float* __restrict__ s3,
    const float* __restrict__ t3, const float* __restrict__ m3, const float* __restrict__ v3,
    const float* __restrict__ w4,
    short* __restrict__ w4T,
    short* __restrict__ gbuf, short* __restrict__ fbufT, short* __restrict__ hhbuf)
{
    __shared__ __align__(16) short Wl[96 * 64];    // [oc][k] swz64, 12KB
    __shared__ __align__(16) short Xl[128 * 64];   // [p][k]  swz64, 16KB
    __shared__ float alB[96], beB[96];

    const int t = threadIdx.x;
    const int lane = t & 63, wv = t >> 6;
    const int quad = lane >> 4, l16 = lane & 15;
    const int ptile = blockIdx.x;     // 0..31 (row pair)
    const int ocg   = blockIdx.y;     // 0..1
    const int bz    = blockIdx.z;
    const int pBase = ptile * 128;
    const int wcol  = (wv & 1) * 32;  // wave's column half
    const int woch  = (wv >> 1) * 48; // wave's oc half

    // w4 -> bf16, once (32 blocks x 256 threads x 4 elems = 32768)
    if (ocg == 0 && bz == 0) {
        int idx = (ptile * 256 + t) * 4;
        float4 a = *(const float4*)(w4 + idx);
        short4 o;
        o.x = f2bs(a.x); o.y = f2bs(a.y); o.z = f2bs(a.z); o.w = f2bs(a.w);
        *(short4*)&w4T[idx] = o;
    }

    if (t < 96) {
        int j = ocg * 96 + t;
        float pb, ps, ptv, pm, pv;
        if (j < 32)      { pb = b1[j]; ps = s1[j]; ptv = t1[j]; pm = m1[j]; pv = v1[j]; }
        else if (j < 64) { int c = j - 32; pb = b2[c]; ps = s2[c]; ptv = t2[c]; pm = m2[c]; pv = v2[c]; }
        else             { int c = j - 64; pb = b3[c]; ps = s3[c]; ptv = t3[c]; pm = m3[c]; pv = v3[c]; }
        float al = ps * rsqrtf(pv + EPS);
        alB[t] = al; beB[t] = (pb - pm) * al + ptv;
    }

    const f32x4 fzero = {0.f, 0.f, 0.f, 0.f};
    f32x4 acc[3][4];                  // [oc-tile][p-tile]
    #pragma unroll
    for (int i = 0; i < 3; ++i)
        #pragma unroll
        for (int j = 0; j < 4; ++j) acc[i][j] = fzero;

    const int ptOff0 = wcol, ptOff1 = wcol + 16, ptOff2 = wcol + 64, ptOff3 = wcol + 80;
    const int xp  = t & 127, xk8 = t >> 7;

    for (int k0 = 0; k0 < 256; k0 += 64) {
        #pragma unroll
        for (int i = 0; i < 2; ++i) {
            int idx = t + i * 256;
            if (i == 0 || t < 128) {
                int oc = idx >> 2, kb = (idx & 3) * 16;
                int j = ocg * 96 + oc;
                const float* wp = (j < 32) ? (w1 + j * 256)
                                : (j < 64) ? (w2 + (j - 32) * 256)
                                           : (w3 + (j - 64) * 256);
                wp += k0 + kb;
                float4 a = *(const float4*)(wp);
                float4 b = *(const float4*)(wp + 4);
                float4 c = *(const float4*)(wp + 8);
                float4 d = *(const float4*)(wp + 12);
                bf16x8 lo, hi;
                lo[0]=f2bs(a.x); lo[1]=f2bs(a.y); lo[2]=f2bs(a.z); lo[3]=f2bs(a.w);
                lo[4]=f2bs(b.x); lo[5]=f2bs(b.y); lo[6]=f2bs(b.z); lo[7]=f2bs(b.w);
                hi[0]=f2bs(c.x); hi[1]=f2bs(c.y); hi[2]=f2bs(c.z); hi[3]=f2bs(c.w);
                hi[4]=f2bs(d.x); hi[5]=f2bs(d.y); hi[6]=f2bs(d.z); hi[7]=f2bs(d.w);
                *(bf16x8*)&Wl[swz64(oc, (kb >> 3))]     = lo;
                *(bf16x8*)&Wl[swz64(oc, (kb >> 3) + 1)] = hi;
            }
        }
        {
            const float* xp0 = x + ((size_t)bz * 256 + k0 + xk8 * 32) * HW + pBase + xp;
            float fv[32];
            #pragma unroll
            for (int i = 0; i < 32; ++i) fv[i] = xp0[(size_t)i * HW];
            #pragma unroll
            for (int c = 0; c < 4; ++c) {
                bf16x8 v;
                #pragma unroll
                for (int jj = 0; jj < 8; ++jj) v[jj] = f2bs(fv[c * 8 + jj]);
                *(bf16x8*)&Xl[swz64(xp, xk8 * 4 + c)] = v;
            }
        }
        __syncthreads();
        #pragma unroll
        for (int kk = 0; kk < 2; ++kk) {
            bf16x8 bfr[4];
            bfr[0] = *(const bf16x8*)&Xl[swz64(ptOff0 + l16, kk * 4 + quad)];
            bfr[1] = *(const bf16x8*)&Xl[swz64(ptOff1 + l16, kk * 4 + quad)];
            bfr[2] = *(const bf16x8*)&Xl[swz64(ptOff2 + l16, kk * 4 + quad)];
            bfr[3] = *(const bf16x8*)&Xl[swz64(ptOff3 + l16, kk * 4 + quad)];
            #pragma unroll
            for (int tt = 0; tt < 3; ++tt) {
                bf16x8 afr = *(const bf16x8*)&Wl[swz64(woch + tt * 16 + l16, kk * 4 + quad)];
                #pragma unroll
                for (int pt = 0; pt < 4; ++pt)
                    acc[tt][pt] = __builtin_amdgcn_mfma_f32_16x16x32_bf16(afr, bfr[pt], acc[tt][pt], 0, 0, 0);
            }
        }
        __syncthreads();
    }

    #pragma unroll
    for (int tt = 0; tt < 3; ++tt) {
        #pragma unroll
        for (int r = 0; r < 4; ++r) {
            int ocl = woch + tt * 16 + quad * 4 + r;
            int j = ocg * 96 + ocl;
            float al = alB[ocl], be = beB[ocl];
            float y[4];
            y[0] = fmaxf(acc[tt][0][r] * al + be, 0.f);
            y[1] = fmaxf(acc[tt][1][r] * al + be, 0.f);
            y[2] = fmaxf(acc[tt][2][r] * al + be, 0.f);
            y[3] = fmaxf(acc[tt][3][r] * al + be, 0.f);
            if (j >= 32 && j < 64) {        // g: store unpooled
                size_t base = ((size_t)bz * 32 + (j - 32)) * HW + pBase;
                gbuf[base + ptOff0 + l16] = f2bs(y[0]);
                gbuf[base + ptOff1 + l16] = f2bs(y[1]);
                gbuf[base + ptOff2 + l16] = f2bs(y[2]);
                gbuf[base + ptOff3 + l16] = f2bs(y[3]);
            } else {                        // f / hh: 2x2 maxpool
                #pragma unroll
                for (int c = 0; c < 2; ++c) {
                    float v  = fmaxf(y[c], y[c + 2]);
                    float po = fmaxf(v, __shfl_xor(v, 1));
                    if ((l16 & 1) == 0) {
                        int col = wcol + c * 16 + l16;
                        int n = ptile * 32 + (col >> 1);
                        if (j < 32) fbufT[((size_t)bz * 1024 + n) * 32 + j] = f2bs(po);  // transposed [n][k]
                        else        hhbuf[((size_t)bz * 128 + (j - 64)) * HW4 + n] = f2bs(po);
                    }
                }
            }
        }
    }
}

// ---------------------------------------------------------------------------
// Kernel 2: fused attention (constant-shift softmax) + conv4 + BN + residual.
// Grid (64 mtile, 8 bz) = 512 blocks.
// Pipelined n-loop: ONE barrier per iteration, hh double-buffered in LDS with
// register prefetch (T14), f-fragments loaded straight from fbufT (coalesced
// 16B, 1-tile register lookahead). Phase 2 uses pre-converted bf16 w4T with a
// register-prefetched W tile.
// LDS: phase1 gTl(2560) sTl(4096) hh0(8192) hh1(8192) = 23040 shorts (45KB).
// ---------------------------------------------------------------------------
__global__ __launch_bounds__(256, 2) void attn_conv4(
    const short* __restrict__ gbuf,
    const short* __restrict__ fbufT,
    const short* __restrict__ hhbuf,
    const float* __restrict__ x,
    const short* __restrict__ w4T, const float* __restrict__ b4, const float* __restrict__ s4,
    const float* __restrict__ t4, const float* __restrict__ m4, const float* __restrict__ v4,
    const float* __restrict__ gamma, float* __restrict__ out)
{
    __shared__ __align__(16) short smem[23040];    // 46080 B
    __shared__ float alB4[256], beB4[256];
    short* gTl  = smem;            // [64m][32k]  p40,   2560 shorts (phase 1)
    short* sTl  = smem + 2560;     // [64m][64n]  swz64, 4096 (beta^T, unnormalized)
    short* hhl0 = smem + 6656;     // [128c][64n] swz64, 8192 (double buffer A)
    short* hhl1 = smem + 14848;    // [128c][64n] swz64, 8192 (double buffer B)
    short* o_l  = smem;            // [64m][128c] swz128, 8192 (phase 2)
    short* Wl4  = smem + 8192;     // [256oc][32k] p40, 10240 (phase 2)

    const int t = threadIdx.x;
    const int lane = t & 63, wv = t >> 6;
    const int quad = lane >> 4, l16 = lane & 15;
    const int bz = blockIdx.y;
    const int m0 = blockIdx.x * 64;
    const int ms = wv * 16;
    const f32x4 fzero = {0.f, 0.f, 0.f, 0.f};

    {   // conv4 BN constants
        float al = s4[t] * rsqrtf(v4[t] + EPS);
        alB4[t] = al; beB4[t] = (b4[t] - m4[t]) * al + t4[t];
    }

    const short* fT = fbufT + (size_t)bz * 1024 * 32;
    const short* hB = hhbuf + (size_t)bz * 128 * HW4;
    const int hrow = t >> 3, hnc = t & 7;

    // --- prologue prefetch: tile 0 f-fragments + hh tile into registers ---
    bf16x8 fr[4], hr[4];
    #pragma unroll
    for (int nt = 0; nt < 4; ++nt)
        fr[nt] = *(const bf16x8*)&fT[(nt * 16 + l16) * 32 + quad * 8];
    #pragma unroll
    for (int i = 0; i < 4; ++i)
        hr[i] = *(const bf16x8*)(hB + (size_t)(i * 32 + hrow) * HW4 + hnc * 8);

    // stage g^T once: gTl[m][k]
    {
        int mm = t & 63, k8 = t >> 6;
        bf16x8 v;
        #pragma unroll
        for (int j = 0; j < 8; ++j)
            v[j] = gbuf[((size_t)bz * 32 + k8 * 8 + j) * HW + m0 + mm];
        *(bf16x8*)&gTl[p40(mm, k8)] = v;
    }
    __syncthreads();
    bf16x8 bg = *(const bf16x8*)&gTl[p40(ms + l16, quad)];   // loop-invariant B-frag

    float psum = 0.f;
    f32x4 oacc[8];
    #pragma unroll
    for (int i = 0; i < 8; ++i) oacc[i] = fzero;

    // --- main n-loop: 1 barrier/iter, hh double-buffered, all loads 1 tile ahead ---
    #pragma unroll 2
    for (int it = 0; it < 16; ++it) {
        const int n0n = ((it + 1) & 15) << 6;     // next tile (wraps; wrap loads are dead)
        short* hb = (it & 1) ? hhl1 : hhl0;

        // commit current hh tile (prefetched last iter) to this iter's buffer
        #pragma unroll
        for (int i = 0; i < 4; ++i)
            *(bf16x8*)&hb[swz64(i * 32 + hrow, hnc)] = hr[i];
        // issue next hh tile loads (land during this iter's compute)
        #pragma unroll
        for (int i = 0; i < 4; ++i)
            hr[i] = *(const bf16x8*)(hB + (size_t)(i * 32 + hrow) * HW4 + n0n + hnc * 8);
        __syncthreads();

        // s-phase: s[n][m] for wave's 16-m strip (f-frags already in regs)
        f32x4 sacc[4];
        #pragma unroll
        for (int nt = 0; nt < 4; ++nt)
            sacc[nt] = __builtin_amdgcn_mfma_f32_16x16x32_bf16(fr[nt], bg, fzero, 0, 0, 0);
        // issue next f-fragment loads (consumed after next barrier)
        #pragma unroll
        for (int nt = 0; nt < 4; ++nt)
            fr[nt] = *(const bf16x8*)&fT[(n0n + nt * 16 + l16) * 32 + quad * 8];

        // exp(s - C), per-lane partial sum; no cross-lane ops, no rescale
        #pragma unroll
        for (int nt = 0; nt < 4; ++nt) {
            short4 ev;
            #pragma unroll
            for (int r = 0; r < 4; ++r) {
                float e = __expf(sacc[nt][r] - SM_SHIFT);
                psum += e;
                ((short*)&ev)[r] = f2bs(e);
            }
            int chunk = nt * 2 + (quad >> 1);
            *(short4*)&sTl[swz64(ms + l16, chunk) + (quad & 1) * 4] = ev;   // beta^T[m][n]
        }

        // o-phase: o[c][m] += hh[c][n] * beta[n][m]; wave reads own sTl rows only
        #pragma unroll
        for (int kk = 0; kk < 2; ++kk) {
            bf16x8 bs = *(const bf16x8*)&sTl[swz64(ms + l16, kk * 4 + quad)];
            #pragma unroll
            for (int ct = 0; ct < 8; ++ct) {
                bf16x8 ah = *(const bf16x8*)&hb[swz64(ct * 16 + l16, kk * 4 + quad)];
                oacc[ct] = __builtin_amdgcn_mfma_f32_16x16x32_bf16(ah, bs, oacc[ct], 0, 0, 0);
            }
        }
    }
    __syncthreads();   // all attn LDS reads complete

    // normalize in-register: Z for m = ms+l16 (reduce psum across quads)
    psum += __shfl_xor(psum, 16);
    psum += __shfl_xor(psum, 32);
    {
        float inv = 1.0f / psum;
        int m = ms + l16;
        #pragma unroll
        for (int ct = 0; ct < 8; ++ct) {
            short4 ov;
            #pragma unroll
            for (int r = 0; r < 4; ++r) ((short*)&ov)[r] = f2bs(oacc[ct][r] * inv);
            *(short4*)&o_l[swz128(m, ct * 2 + (quad >> 1)) + (quad & 1) * 4] = ov;
        }
    }

    // conv4: out[oc][m] = W4(256x128) . o(128x64m); W4 pre-converted bf16,
    // staged per 32-k chunk with register prefetch.
    f32x4 acc4[4][4];
    #pragma unroll
    for (int i = 0; i < 4; ++i)
        #pragma unroll
        for (int j = 0; j < 4; ++j) acc4[i][j] = fzero;

    const int wrow = t >> 2, wcid = t & 3;
    bf16x8 Wr[4];
    #pragma unroll
    for (int g = 0; g < 4; ++g)
        Wr[g] = *(const bf16x8*)(w4T + (g * 64 + wrow) * 128 + wcid * 8);

    #pragma unroll
    for (int k0i = 0; k0i < 4; ++k0i) {
        const int k0 = k0i * 32;
        __syncthreads();   // o_l ready (first iter) / prior Wl4 readers done
        #pragma unroll
        for (int g = 0; g < 4; ++g)
            *(bf16x8*)&Wl4[p40(g * 64 + wrow, wcid)] = Wr[g];
        if (k0i < 3) {
            #pragma unroll
            for (int g = 0; g < 4; ++g)
                Wr[g] = *(const bf16x8*)(w4T + (g * 64 + wrow) * 128 + k0 + 32 + wcid * 8);
        }
        __syncthreads();
        bf16x8 bfr[4];
        #pragma unroll
        for (int mt = 0; mt < 4; ++mt)
            bfr[mt] = *(const bf16x8*)&o_l[swz128(mt * 16 + l16, (k0 >> 3) + quad)];
        #pragma unroll
        for (int ot = 0; ot < 4; ++ot) {
            bf16x8 afr = *(const bf16x8*)&Wl4[p40(wv * 64 + ot * 16 + l16, quad)];
            #pragma unroll
            for (int mt = 0; mt < 4; ++mt)
                acc4[ot][mt] = __builtin_amdgcn_mfma_f32_16x16x32_bf16(afr, bfr[mt], acc4[ot][mt], 0, 0, 0);
        }
    }

    float gm = gamma[0];
    #pragma unroll
    for (int ot = 0; ot < 4; ++ot) {
        #pragma unroll
        for (int r = 0; r < 4; ++r) {
            int oc = wv * 64 + ot * 16 + quad * 4 + r;
            float al = alB4[oc], be = beB4[oc];
            #pragma unroll
            for (int mt = 0; mt < 4; ++mt) {
                int p = m0 + mt * 16 + l16;
                float y  = acc4[ot][mt][r] * al + be;
                float xo = x[((size_t)bz * 256 + oc) * HW + p];
                out[((size_t)bz * 256 + oc) * HW + p] = gm * y + xo;
            }
        }
    }
}

extern "C" void kernel_launch(void* const* d_in, const int* in_sizes, int n_in,
                              void* d_out, int out_size, void* d_ws, size_t ws_size,
                              hipStream_t stream)
{
    const float* x  = (const float*)d_in[0];
    const float* w1 = (const float*)d_in[1];
    const float* b1 = (const float*)d_in[2];
    const float* s1 = (const float*)d_in[3];
    const float* t1 = (const float*)d_in[4];
    const float* m1 = (const float*)d_in[5];
    const float* v1 = (const float*)d_in[6];
    const float* w2 = (const float*)d_in[7];
    const float* b2 = (const float*)d_in[8];
    const float* s2 = (const float*)d_in[9];
    const float* t2 = (const float*)d_in[10];
    const float* m2 = (const float*)d_in[11];
    const float* v2 = (const float*)d_in[12];
    const float* w3 = (const float*)d_in[13];
    const float* b3 = (const float*)d_in[14];
    const float* s3 = (const float*)d_in[15];
    const float* t3 = (const float*)d_in[16];
    const float* m3 = (const float*)d_in[17];
    const float* v3 = (const float*)d_in[18];
    const float* w4 = (const float*)d_in[19];
    const float* b4 = (const float*)d_in[20];
    const float* s4 = (const float*)d_in[21];
    const float* t4 = (const float*)d_in[22];
    const float* m4 = (const float*)d_in[23];
    const float* v4 = (const float*)d_in[24];
    const float* gm = (const float*)d_in[25];
    float* out = (float*)d_out;

    short* gbuf  = (short*)d_ws;                     // 8*32*4096 bf16 (2 MB)
    short* fbufT = gbuf  + (size_t)8 * 32 * 4096;    // 8*1024*32  (0.5 MB, [n][k])
    short* hhbuf = fbufT + (size_t)8 * 1024 * 32;    // 8*128*1024 (2 MB)
    short* w4T   = hhbuf + (size_t)8 * 128 * 1024;   // 256*128 bf16 (64 KB)

    conv123pool<<<dim3(32, 2, 8), 256, 0, stream>>>(
        x, w1, b1, s1, t1, m1, v1, w2, b2, s2, t2, m2, v2, w3, b3, s3, t3, m3, v3,
        w4, w4T, gbuf, fbufT, hhbuf);
    attn_conv4<<<dim3(64, 8), 256, 0, stream>>>(
        gbuf, fbufT, hhbuf, x, w4T, b4, s4, t4, m4, v4, gm, out);
}

// Round 3
// 160.321 us; speedup vs baseline: 1.0688x; 1.0253x over previous
//
#include <hip/hip_runtime.h>
#include <hip/hip_bf16.h>

#define HW   4096
#define HW4  1024
#define EPS  1e-5f
#define SM_SHIFT 20.0f   // constant-shift softmax: exp(s - SM_SHIFT); |s| << 20 by construction

typedef __attribute__((ext_vector_type(8)))  short    bf16x8;   // 8 bf16 (4 VGPRs)
typedef __attribute__((ext_vector_type(4)))  float    f32x4;    // MFMA C/D 16x16

__device__ __forceinline__ short f2bs(float f) {            // fp32 -> bf16 bits (RNE)
    union { float f; unsigned u; } v; v.f = f;
    unsigned r = v.u + 0x7FFFu + ((v.u >> 16) & 1u);
    return (short)(r >> 16);
}
// XOR-swizzled LDS layouts (16B chunks permuted by row), row strides 64/128 shorts.
__device__ __forceinline__ int swz64(int r, int c)  { return (r << 6) + ((c ^ (r & 7))  << 3); }
__device__ __forceinline__ int swz128(int r, int c) { return (r << 7) + ((c ^ (r & 15)) << 3); }
// Padded 40-short (80B) rows.
__device__ __forceinline__ int p40(int r, int c)    { return r * 40 + c * 8; }

// ---------------------------------------------------------------------------
// Kernel 1: conv1x1+BN+ReLU branches 1-3, 2x2 maxpool fused in registers.
// Grid (32 ptile, 2 ocg, 8 bz) = 512 blocks -> 2 blocks/CU.
// X-tile register ping-pong prefetch (next 64-k chunk's loads issued during
// current chunk's convert+MFMA). g stored TRANSPOSED (gbufT[m][k]) so kernel2
// loads its loop-invariant B-frag straight from global, coalesced.
// ---------------------------------------------------------------------------
__global__ __launch_bounds__(256) void conv123pool(
    const float* __restrict__ x,
    const float* __restrict__ w1, const float* __restrict__ b1, const float* __restrict__ s1,
    const float* __restrict__ t1, const float* __restrict__ m1, const float* __restrict__ v1,
    const float* __restrict__ w2, const float* __restrict__ b2, const float* __restrict__ s2,
    const float* __restrict__ t2, const float* __restrict__ m2, const float* __restrict__ v2,
    const float* __restrict__ w3, const float* __restrict__ b3, const float* __restrict__ s3,
    const float* __restrict__ t3, const float* __restrict__ m3, const float* __restrict__ v3,
    const float* __restrict__ w4,
    short* __restrict__ w4T,
    short* __restrict__ gbufT, short* __restrict__ fbufT, short* __restrict__ hhbuf)
{
    __shared__ __align__(16) short Wl[96 * 64];    // [oc][k] swz64, 12KB
    __shared__ __align__(16) short Xl[128 * 64];   // [p][k]  swz64, 16KB
    __shared__ float alB[96], beB[96];

    const int t = threadIdx.x;
    const int lane = t & 63, wv = t >> 6;
    const int quad = lane >> 4, l16 = lane & 15;
    const int ptile = blockIdx.x;     // 0..31 (row pair)
    const int ocg   = blockIdx.y;     // 0..1
    const int bz    = blockIdx.z;
    const int pBase = ptile * 128;
    const int wcol  = (wv & 1) * 32;  // wave's column half
    const int woch  = (wv >> 1) * 48; // wave's oc half

    // w4 -> bf16, once (32 blocks x 256 threads x 4 elems = 32768)
    if (ocg == 0 && bz == 0) {
        int idx = (ptile * 256 + t) * 4;
        float4 a = *(const float4*)(w4 + idx);
        short4 o;
        o.x = f2bs(a.x); o.y = f2bs(a.y); o.z = f2bs(a.z); o.w = f2bs(a.w);
        *(short4*)&w4T[idx] = o;
    }

    if (t < 96) {
        int j = ocg * 96 + t;
        float pb, ps, ptv, pm, pv;
        if (j < 32)      { pb = b1[j]; ps = s1[j]; ptv = t1[j]; pm = m1[j]; pv = v1[j]; }
        else if (j < 64) { int c = j - 32; pb = b2[c]; ps = s2[c]; ptv = t2[c]; pm = m2[c]; pv = v2[c]; }
        else             { int c = j - 64; pb = b3[c]; ps = s3[c]; ptv = t3[c]; pm = m3[c]; pv = v3[c]; }
        float al = ps * rsqrtf(pv + EPS);
        alB[t] = al; beB[t] = (pb - pm) * al + ptv;
    }

    const f32x4 fzero = {0.f, 0.f, 0.f, 0.f};
    f32x4 acc[3][4];                  // [oc-tile][p-tile]
    #pragma unroll
    for (int i = 0; i < 3; ++i)
        #pragma unroll
        for (int j = 0; j < 4; ++j) acc[i][j] = fzero;

    const int ptOff0 = wcol, ptOff1 = wcol + 16, ptOff2 = wcol + 64, ptOff3 = wcol + 80;
    const int xp  = t & 127, xk8 = t >> 7;
    const float* xBase = x + ((size_t)bz * 256 + xk8 * 32) * HW + pBase + xp;

    float fvA[32], fvB[32];
    #pragma unroll
    for (int i = 0; i < 32; ++i) fvA[i] = xBase[(size_t)i * HW];

#define K1_CHUNK(KC, CUR, NXT)                                                        \
    {                                                                                 \
        _Pragma("unroll")                                                             \
        for (int i = 0; i < 2; ++i) {                                                 \
            int idx = t + i * 256;                                                    \
            if (i == 0 || t < 128) {                                                  \
                int oc = idx >> 2, kb = (idx & 3) * 16;                               \
                int j = ocg * 96 + oc;                                                \
                const float* wp = (j < 32) ? (w1 + j * 256)                           \
                                : (j < 64) ? (w2 + (j - 32) * 256)                    \
                                           : (w3 + (j - 64) * 256);                   \
                wp += (KC) * 64 + kb;                                                 \
                float4 a = *(const float4*)(wp);                                      \
                float4 b = *(const float4*)(wp + 4);                                  \
                float4 c = *(const float4*)(wp + 8);                                  \
                float4 d = *(const float4*)(wp + 12);                                 \
                bf16x8 lo, hi;                                                        \
                lo[0]=f2bs(a.x); lo[1]=f2bs(a.y); lo[2]=f2bs(a.z); lo[3]=f2bs(a.w);   \
                lo[4]=f2bs(b.x); lo[5]=f2bs(b.y); lo[6]=f2bs(b.z); lo[7]=f2bs(b.w);   \
                hi[0]=f2bs(c.x); hi[1]=f2bs(c.y); hi[2]=f2bs(c.z); hi[3]=f2bs(c.w);   \
                hi[4]=f2bs(d.x); hi[5]=f2bs(d.y); hi[6]=f2bs(d.z); hi[7]=f2bs(d.w);   \
                *(bf16x8*)&Wl[swz64(oc, (kb >> 3))]     = lo;                         \
                *(bf16x8*)&Wl[swz64(oc, (kb >> 3) + 1)] = hi;                         \
            }                                                                         \
        }                                                                             \
        if ((KC) < 3) {                                                               \
            const float* xn = xBase + (size_t)(((KC) + 1) * 64) * HW;                 \
            _Pragma("unroll")                                                         \
            for (int i2 = 0; i2 < 32; ++i2) NXT[i2] = xn[(size_t)i2 * HW];            \
        }                                                                             \
        _Pragma("unroll")                                                             \
        for (int c2 = 0; c2 < 4; ++c2) {                                              \
            bf16x8 v;                                                                 \
            _Pragma("unroll")                                                         \
            for (int jj = 0; jj < 8; ++jj) v[jj] = f2bs(CUR[c2 * 8 + jj]);            \
            *(bf16x8*)&Xl[swz64(xp, xk8 * 4 + c2)] = v;                               \
        }                                                                             \
        __syncthreads();                                                              \
        _Pragma("unroll")                                                             \
        for (int kk = 0; kk < 2; ++kk) {                                              \
            bf16x8 bfr[4];                                                            \
            bfr[0] = *(const bf16x8*)&Xl[swz64(ptOff0 + l16, kk * 4 + quad)];         \
            bfr[1] = *(const bf16x8*)&Xl[swz64(ptOff1 + l16, kk * 4 + quad)];         \
            bfr[2] = *(const bf16x8*)&Xl[swz64(ptOff2 + l16, kk * 4 + quad)];         \
            bfr[3] = *(const bf16x8*)&Xl[swz64(ptOff3 + l16, kk * 4 + quad)];         \
            _Pragma("unroll")                                                         \
            for (int tt = 0; tt < 3; ++tt) {                                          \
                bf16x8 afr = *(const bf16x8*)&Wl[swz64(woch + tt*16 + l16, kk*4 + quad)]; \
                _Pragma("unroll")                                                     \
                for (int pt = 0; pt < 4; ++pt)                                        \
                    acc[tt][pt] = __builtin_amdgcn_mfma_f32_16x16x32_bf16(afr, bfr[pt], acc[tt][pt], 0, 0, 0); \
            }                                                                         \
        }                                                                             \
        __syncthreads();                                                              \
    }

    K1_CHUNK(0, fvA, fvB)
    K1_CHUNK(1, fvB, fvA)
    K1_CHUNK(2, fvA, fvB)
    K1_CHUNK(3, fvB, fvA)
#undef K1_CHUNK

    #pragma unroll
    for (int tt = 0; tt < 3; ++tt) {
        #pragma unroll
        for (int r = 0; r < 4; ++r) {
            int ocl = woch + tt * 16 + quad * 4 + r;
            int j = ocg * 96 + ocl;
            float al = alB[ocl], be = beB[ocl];
            float y[4];
            y[0] = fmaxf(acc[tt][0][r] * al + be, 0.f);
            y[1] = fmaxf(acc[tt][1][r] * al + be, 0.f);
            y[2] = fmaxf(acc[tt][2][r] * al + be, 0.f);
            y[3] = fmaxf(acc[tt][3][r] * al + be, 0.f);
            if (j >= 32 && j < 64) {        // g: store TRANSPOSED [m][k]
                size_t mb = (size_t)bz * 4096 + pBase;
                int kk = j - 32;
                gbufT[(mb + ptOff0 + l16) * 32 + kk] = f2bs(y[0]);
                gbufT[(mb + ptOff1 + l16) * 32 + kk] = f2bs(y[1]);
                gbufT[(mb + ptOff2 + l16) * 32 + kk] = f2bs(y[2]);
                gbufT[(mb + ptOff3 + l16) * 32 + kk] = f2bs(y[3]);
            } else {                        // f / hh: 2x2 maxpool
                #pragma unroll
                for (int c = 0; c < 2; ++c) {
                    float v  = fmaxf(y[c], y[c + 2]);
                    float po = fmaxf(v, __shfl_xor(v, 1));
                    if ((l16 & 1) == 0) {
                        int col = wcol + c * 16 + l16;
                        int n = ptile * 32 + (col >> 1);
                        if (j < 32) fbufT[((size_t)bz * 1024 + n) * 32 + j] = f2bs(po);  // [n][k]
                        else        hhbuf[((size_t)bz * 128 + (j - 64)) * HW4 + n] = f2bs(po);
                    }
                }
            }
        }
    }
}

// ---------------------------------------------------------------------------
// Kernel 2: fused attention (constant-shift softmax) + conv4 + BN + residual.
// Grid (64 mtile, 8 bz) = 512 blocks, 256 threads.
// s-phase: wave wv computes s for m-strip wv (16x16x32, all 64 n of the tile).
// o-phase: wave wv owns c-slice [wv*32, wv*32+32) x ALL 64 m (reads other
// waves' beta rows through LDS) -> 12 ds_read_b128 + 16 MFMA per iter/wave
// (was 18 + 16). hh and beta double-buffered, ONE barrier per iteration,
// hh/f prefetched one tile ahead in registers. Cross-wave Z via Zl[64].
// ---------------------------------------------------------------------------
__global__ __launch_bounds__(256, 2) void attn_conv4(
    const short* __restrict__ gbufT,
    const short* __restrict__ fbufT,
    const short* __restrict__ hhbuf,
    const float* __restrict__ x,
    const short* __restrict__ w4T, const float* __restrict__ b4, const float* __restrict__ s4,
    const float* __restrict__ t4, const float* __restrict__ m4, const float* __restrict__ v4,
    const float* __restrict__ gamma, float* __restrict__ out)
{
    __shared__ __align__(16) short smem[24576];    // 48 KB
    __shared__ float alB4[256], beB4[256];
    __shared__ float Zl[64];
    short* sT0  = smem;            // [64m][64n] swz64 beta^T, 4096 sh (dbuf A)
    short* sT1  = smem + 4096;     //                          (dbuf B)
    short* hhl0 = smem + 8192;     // [128c][64n] swz64, 8192 sh (dbuf A)
    short* hhl1 = smem + 16384;    //                           (dbuf B)
    short* o_l  = smem;            // phase2: [64m][128c] swz128, 8192 sh
    short* Wl4  = smem + 8192;     // phase2: [256oc][32k] p40, 10240 sh

    const int t = threadIdx.x;
    const int lane = t & 63, wv = t >> 6;
    const int quad = lane >> 4, l16 = lane & 15;
    const int bz = blockIdx.y;
    const int m0 = blockIdx.x * 64;
    const f32x4 fzero = {0.f, 0.f, 0.f, 0.f};

    {   // conv4 BN constants
        float al = s4[t] * rsqrtf(v4[t] + EPS);
        alB4[t] = al; beB4[t] = (b4[t] - m4[t]) * al + t4[t];
    }

    const short* fT = fbufT + (size_t)bz * 1024 * 32;
    const short* hB = hhbuf + (size_t)bz * 128 * HW4;
    const int hrow = t >> 3, hnc = t & 7;

    // loop-invariant B-frag for s-phase: g^T[m0 + wv*16 + l16][quad*8..]
    bf16x8 bg = *(const bf16x8*)&gbufT[((size_t)bz * 4096 + m0 + wv * 16 + l16) * 32 + quad * 8];

    // prologue prefetch: tile 0 f-frags + hh tile in registers
    bf16x8 fr[4], hr[4];
    #pragma unroll
    for (int nt = 0; nt < 4; ++nt)
        fr[nt] = *(const bf16x8*)&fT[(nt * 16 + l16) * 32 + quad * 8];
    #pragma unroll
    for (int i = 0; i < 4; ++i)
        hr[i] = *(const bf16x8*)(hB + (size_t)(i * 32 + hrow) * HW4 + hnc * 8);

    float psum = 0.f;
    f32x4 oacc[2][4];              // [c-tile within slice][m-tile]
    #pragma unroll
    for (int a = 0; a < 2; ++a)
        #pragma unroll
        for (int b = 0; b < 4; ++b) oacc[a][b] = fzero;

    #pragma unroll 2
    for (int it = 0; it < 16; ++it) {
        const int n0n = ((it + 1) & 15) << 6;     // next tile (wraps; wrap loads dead)
        short* hb = (it & 1) ? hhl1 : hhl0;
        short* sT = (it & 1) ? sT1  : sT0;

        // commit current hh tile; issue next tile's loads
        #pragma unroll
        for (int i = 0; i < 4; ++i)
            *(bf16x8*)&hb[swz64(i * 32 + hrow, hnc)] = hr[i];
        #pragma unroll
        for (int i = 0; i < 4; ++i)
            hr[i] = *(const bf16x8*)(hB + (size_t)(i * 32 + hrow) * HW4 + n0n + hnc * 8);

        // s-phase: strip wv, all 64 n of this tile
        f32x4 sacc[4];
        #pragma unroll
        for (int nt = 0; nt < 4; ++nt)
            sacc[nt] = __builtin_amdgcn_mfma_f32_16x16x32_bf16(fr[nt], bg, fzero, 0, 0, 0);
        #pragma unroll
        for (int nt = 0; nt < 4; ++nt)
            fr[nt] = *(const bf16x8*)&fT[(n0n + nt * 16 + l16) * 32 + quad * 8];

        // exp(s - C), per-lane partial sum over n; store beta^T slice
        #pragma unroll
        for (int nt = 0; nt < 4; ++nt) {
            short4 ev;
            #pragma unroll
            for (int r = 0; r < 4; ++r) {
                float e = __expf(sacc[nt][r] - SM_SHIFT);
                psum += e;
                ((short*)&ev)[r] = f2bs(e);
            }
            *(short4*)&sT[swz64(wv * 16 + l16, nt * 2 + (quad >> 1)) + (quad & 1) * 4] = ev;
        }

        __syncthreads();   // hh + beta of this tile visible; prior-iter readers done

        // o-phase: c-slice [wv*32, wv*32+32), all 64 m
        #pragma unroll
        for (int kk = 0; kk < 2; ++kk) {
            bf16x8 ah0 = *(const bf16x8*)&hb[swz64(wv * 32 + l16,      kk * 4 + quad)];
            bf16x8 ah1 = *(const bf16x8*)&hb[swz64(wv * 32 + 16 + l16, kk * 4 + quad)];
            bf16x8 bs[4];
            #pragma unroll
            for (int mt = 0; mt < 4; ++mt)
                bs[mt] = *(const bf16x8*)&sT[swz64(mt * 16 + l16, kk * 4 + quad)];
            #pragma unroll
            for (int mt = 0; mt < 4; ++mt) {
                oacc[0][mt] = __builtin_amdgcn_mfma_f32_16x16x32_bf16(ah0, bs[mt], oacc[0][mt], 0, 0, 0);
                oacc[1][mt] = __builtin_amdgcn_mfma_f32_16x16x32_bf16(ah1, bs[mt], oacc[1][mt], 0, 0, 0);
            }
        }
    }

    // Z per m (wave's s-phase strip): reduce psum across quads, publish
    psum += __shfl_xor(psum, 16);
    psum += __shfl_xor(psum, 32);
    if (quad == 0) Zl[wv * 16 + l16] = psum;
    __syncthreads();   // all attn LDS reads complete + Zl visible

    // normalize + write o_l (bf16, swz128 [m][c]); wave covers its c-slice, all m
    #pragma unroll
    for (int mt = 0; mt < 4; ++mt) {
        float iv = 1.0f / Zl[mt * 16 + l16];
        #pragma unroll
        for (int ct2 = 0; ct2 < 2; ++ct2) {
            short4 ov;
            #pragma unroll
            for (int r = 0; r < 4; ++r) ((short*)&ov)[r] = f2bs(oacc[ct2][mt][r] * iv);
            *(short4*)&o_l[swz128(mt * 16 + l16, wv * 4 + ct2 * 2 + (quad >> 1)) + (quad & 1) * 4] = ov;
        }
    }

    // conv4: out[oc][m] = W4(256x128) . o(128x64m); W4 pre-converted bf16,
    // staged per 32-k chunk with register prefetch.
    f32x4 acc4[4][4];
    #pragma unroll
    for (int i = 0; i < 4; ++i)
        #pragma unroll
        for (int j = 0; j < 4; ++j) acc4[i][j] = fzero;

    const int wrow = t >> 2, wcid = t & 3;
    bf16x8 Wr[4];
    #pragma unroll
    for (int g = 0; g < 4; ++g)
        Wr[g] = *(const bf16x8*)(w4T + (g * 64 + wrow) * 128 + wcid * 8);

    #pragma unroll
    for (int k0i = 0; k0i < 4; ++k0i) {
        const int k0 = k0i * 32;
        __syncthreads();   // o_l writes visible (first iter); prior Wl4 readers done
        #pragma unroll
        for (int g = 0; g < 4; ++g)
            *(bf16x8*)&Wl4[p40(g * 64 + wrow, wcid)] = Wr[g];
        if (k0i < 3) {
            #pragma unroll
            for (int g = 0; g < 4; ++g)
                Wr[g] = *(const bf16x8*)(w4T + (g * 64 + wrow) * 128 + k0 + 32 + wcid * 8);
        }
        __syncthreads();
        bf16x8 bfr[4];
        #pragma unroll
        for (int mt = 0; mt < 4; ++mt)
            bfr[mt] = *(const bf16x8*)&o_l[swz128(mt * 16 + l16, (k0 >> 3) + quad)];
        #pragma unroll
        for (int ot = 0; ot < 4; ++ot) {
            bf16x8 afr = *(const bf16x8*)&Wl4[p40(wv * 64 + ot * 16 + l16, quad)];
            #pragma unroll
            for (int mt = 0; mt < 4; ++mt)
                acc4[ot][mt] = __builtin_amdgcn_mfma_f32_16x16x32_bf16(afr, bfr[mt], acc4[ot][mt], 0, 0, 0);
        }
    }

    float gm = gamma[0];
    #pragma unroll
    for (int ot = 0; ot < 4; ++ot) {
        #pragma unroll
        for (int r = 0; r < 4; ++r) {
            int oc = wv * 64 + ot * 16 + quad * 4 + r;
            float al = alB4[oc], be = beB4[oc];
            #pragma unroll
            for (int mt = 0; mt < 4; ++mt) {
                int p = m0 + mt * 16 + l16;
                float y  = acc4[ot][mt][r] * al + be;
                float xo = x[((size_t)bz * 256 + oc) * HW + p];
                out[((size_t)bz * 256 + oc) * HW + p] = gm * y + xo;
            }
        }
    }
}

extern "C" void kernel_launch(void* const* d_in, const int* in_sizes, int n_in,
                              void* d_out, int out_size, void* d_ws, size_t ws_size,
                              hipStream_t stream)
{
    const float* x  = (const float*)d_in[0];
    const float* w1 = (const float*)d_in[1];
    const float* b1 = (const float*)d_in[2];
    const float* s1 = (const float*)d_in[3];
    const float* t1 = (const float*)d_in[4];
    const float* m1 = (const float*)d_in[5];
    const float* v1 = (const float*)d_in[6];
    const float* w2 = (const float*)d_in[7];
    const float* b2 = (const float*)d_in[8];
    const float* s2 = (const float*)d_in[9];
    const float* t2 = (const float*)d_in[10];
    const float* m2 = (const float*)d_in[11];
    const float* v2 = (const float*)d_in[12];
    const float* w3 = (const float*)d_in[13];
    const float* b3 = (const float*)d_in[14];
    const float* s3 = (const float*)d_in[15];
    const float* t3 = (const float*)d_in[16];
    const float* m3 = (const float*)d_in[17];
    const float* v3 = (const float*)d_in[18];
    const float* w4 = (const float*)d_in[19];
    const float* b4 = (const float*)d_in[20];
    const float* s4 = (const float*)d_in[21];
    const float* t4 = (const float*)d_in[22];
    const float* m4 = (const float*)d_in[23];
    const float* v4 = (const float*)d_in[24];
    const float* gm = (const float*)d_in[25];
    float* out = (float*)d_out;

    short* gbufT = (short*)d_ws;                     // 8*4096*32 bf16 (2 MB, [m][k])
    short* fbufT = gbufT + (size_t)8 * 4096 * 32;    // 8*1024*32  (0.5 MB, [n][k])
    short* hhbuf = fbufT + (size_t)8 * 1024 * 32;    // 8*128*1024 (2 MB)
    short* w4T   = hhbuf + (size_t)8 * 128 * 1024;   // 256*128 bf16 (64 KB)

    conv123pool<<<dim3(32, 2, 8), 256, 0, stream>>>(
        x, w1, b1, s1, t1, m1, v1, w2, b2, s2, t2, m2, v2, w3, b3, s3, t3, m3, v3,
        w4, w4T, gbufT, fbufT, hhbuf);
    attn_conv4<<<dim3(64, 8), 256, 0, stream>>>(
        gbufT, fbufT, hhbuf, x, w4T, b4, s4, t4, m4, v4, gm, out);
}

// Round 4
// 158.547 us; speedup vs baseline: 1.0808x; 1.0112x over previous
//
#include <hip/hip_runtime.h>
#include <hip/hip_bf16.h>

#define HW   4096
#define HW4  1024
#define EPS  1e-5f
#define SM_SHIFT 20.0f   // constant-shift softmax: exp(s - SM_SHIFT); |s| << 20 by construction

typedef __attribute__((ext_vector_type(8)))  short    bf16x8;   // 8 bf16 (4 VGPRs)
typedef __attribute__((ext_vector_type(4)))  float    f32x4;    // MFMA C/D 16x16

__device__ __forceinline__ short f2bs(float f) {            // fp32 -> bf16 bits (RNE)
    union { float f; unsigned u; } v; v.f = f;
    unsigned r = v.u + 0x7FFFu + ((v.u >> 16) & 1u);
    return (short)(r >> 16);
}
// XOR-swizzled LDS layouts (16B chunks permuted by row), row strides 64/128 shorts.
__device__ __forceinline__ int swz64(int r, int c)  { return (r << 6) + ((c ^ (r & 7))  << 3); }
__device__ __forceinline__ int swz128(int r, int c) { return (r << 7) + ((c ^ (r & 15)) << 3); }
// Padded 40-short (80B) rows.
__device__ __forceinline__ int p40(int r, int c)    { return r * 40 + c * 8; }

// ---------------------------------------------------------------------------
// Kernel 1: conv1x1+BN+ReLU branches 1-3, 2x2 maxpool fused in registers.
// MERGED ocg: one 512-thread block handles all 192 oc for a 128-p tile.
// Grid (32 ptile, 8 bz) = 256 blocks, 8 waves each (8 waves/CU).
// x is read/converted ONCE (was twice); x staged via float2 (8B/lane) with
// register ping-pong prefetch of the next 64-k chunk. g stored transposed
// (gbufT[m][k]) for kernel2's coalesced B-frag load.
// ---------------------------------------------------------------------------
__global__ __launch_bounds__(512) void conv123pool(
    const float* __restrict__ x,
    const float* __restrict__ w1, const float* __restrict__ b1, const float* __restrict__ s1,
    const float* __restrict__ t1, const float* __restrict__ m1, const float* __restrict__ v1,
    const float* __restrict__ w2, const float* __restrict__ b2, const float* __restrict__ s2,
    const float* __restrict__ t2, const float* __restrict__ m2, const float* __restrict__ v2,
    const float* __restrict__ w3, const float* __restrict__ b3, const float* __restrict__ s3,
    const float* __restrict__ t3, const float* __restrict__ m3, const float* __restrict__ v3,
    const float* __restrict__ w4,
    short* __restrict__ w4T,
    short* __restrict__ gbufT, short* __restrict__ fbufT, short* __restrict__ hhbuf)
{
    __shared__ __align__(16) short Wl[192 * 64];   // [oc][k] swz64, 24KB
    __shared__ __align__(16) short Xl[128 * 64];   // [p][k]  swz64, 16KB
    __shared__ float alB[192], beB[192];

    const int t = threadIdx.x;            // 0..511
    const int lane = t & 63, wv = t >> 6; // wv 0..7
    const int quad = lane >> 4, l16 = lane & 15;
    const int ptile = blockIdx.x;         // 0..31 (row pair)
    const int bz    = blockIdx.y;         // 0..7
    const int pBase = ptile * 128;
    const int wcol  = (wv & 1) * 32;      // wave's column half
    const int woch  = (wv >> 1) * 48;     // wave's oc group: 0,48,96,144

    // X staging: thread covers p = xp2, xp2+1 (float2) x k rows xkg*8..+7
    const int xp2 = (t & 63) * 2, xkg = t >> 6;
    const float* xBase = x + ((size_t)bz * 256 + xkg * 8) * HW + pBase + xp2;

    float2 fvA[8], fvB[8];
    #pragma unroll
    for (int j = 0; j < 8; ++j) fvA[j] = *(const float2*)(xBase + (size_t)j * HW);

    // w4 -> bf16, once (32 blocks x 512 threads x 2 elems = 32768)
    if (bz == 0) {
        int idx = (ptile * 512 + t) * 2;
        float2 a = *(const float2*)(w4 + idx);
        short2 o; o.x = f2bs(a.x); o.y = f2bs(a.y);
        *(short2*)&w4T[idx] = o;
    }

    if (t < 192) {
        int j = t;
        float pb, ps, ptv, pm, pv;
        if (j < 32)      { pb = b1[j]; ps = s1[j]; ptv = t1[j]; pm = m1[j]; pv = v1[j]; }
        else if (j < 64) { int c = j - 32; pb = b2[c]; ps = s2[c]; ptv = t2[c]; pm = m2[c]; pv = v2[c]; }
        else             { int c = j - 64; pb = b3[c]; ps = s3[c]; ptv = t3[c]; pm = m3[c]; pv = v3[c]; }
        float al = ps * rsqrtf(pv + EPS);
        alB[t] = al; beB[t] = (pb - pm) * al + ptv;
    }

    const f32x4 fzero = {0.f, 0.f, 0.f, 0.f};
    f32x4 acc[3][4];                  // [oc-tile][p-tile]
    #pragma unroll
    for (int i = 0; i < 3; ++i)
        #pragma unroll
        for (int j = 0; j < 4; ++j) acc[i][j] = fzero;

    const int ptOff0 = wcol, ptOff1 = wcol + 16, ptOff2 = wcol + 64, ptOff3 = wcol + 80;

#define K1_CHUNK(KC, CUR, NXT)                                                        \
    {                                                                                 \
        _Pragma("unroll")                                                             \
        for (int i = 0; i < 2; ++i) {                                                 \
            int idx = t + i * 512;                                                    \
            if (i == 0 || t < 256) {                                                  \
                int oc = idx >> 2, kb = (idx & 3) * 16;                               \
                const float* wp = (oc < 32) ? (w1 + oc * 256)                         \
                                : (oc < 64) ? (w2 + (oc - 32) * 256)                  \
                                            : (w3 + (oc - 64) * 256);                 \
                wp += (KC) * 64 + kb;                                                 \
                float4 a = *(const float4*)(wp);                                      \
                float4 b = *(const float4*)(wp + 4);                                  \
                float4 c = *(const float4*)(wp + 8);                                  \
                float4 d = *(const float4*)(wp + 12);                                 \
                bf16x8 lo, hi;                                                        \
                lo[0]=f2bs(a.x); lo[1]=f2bs(a.y); lo[2]=f2bs(a.z); lo[3]=f2bs(a.w);   \
                lo[4]=f2bs(b.x); lo[5]=f2bs(b.y); lo[6]=f2bs(b.z); lo[7]=f2bs(b.w);   \
                hi[0]=f2bs(c.x); hi[1]=f2bs(c.y); hi[2]=f2bs(c.z); hi[3]=f2bs(c.w);   \
                hi[4]=f2bs(d.x); hi[5]=f2bs(d.y); hi[6]=f2bs(d.z); hi[7]=f2bs(d.w);   \
                *(bf16x8*)&Wl[swz64(oc, (kb >> 3))]     = lo;                         \
                *(bf16x8*)&Wl[swz64(oc, (kb >> 3) + 1)] = hi;                         \
            }                                                                         \
        }                                                                             \
        if ((KC) < 3) {                                                               \
            const float* xn = xBase + (size_t)(((KC) + 1) * 64) * HW;                 \
            _Pragma("unroll")                                                         \
            for (int j2 = 0; j2 < 8; ++j2) NXT[j2] = *(const float2*)(xn + (size_t)j2 * HW); \
        }                                                                             \
        {                                                                             \
            bf16x8 va, vb;                                                            \
            _Pragma("unroll")                                                         \
            for (int j2 = 0; j2 < 8; ++j2) { va[j2] = f2bs(CUR[j2].x); vb[j2] = f2bs(CUR[j2].y); } \
            *(bf16x8*)&Xl[swz64(xp2,     xkg)] = va;                                  \
            *(bf16x8*)&Xl[swz64(xp2 + 1, xkg)] = vb;                                  \
        }                                                                             \
        __syncthreads();                                                              \
        _Pragma("unroll")                                                             \
        for (int kk = 0; kk < 2; ++kk) {                                              \
            bf16x8 bfr[4];                                                            \
            bfr[0] = *(const bf16x8*)&Xl[swz64(ptOff0 + l16, kk * 4 + quad)];         \
            bfr[1] = *(const bf16x8*)&Xl[swz64(ptOff1 + l16, kk * 4 + quad)];         \
            bfr[2] = *(const bf16x8*)&Xl[swz64(ptOff2 + l16, kk * 4 + quad)];         \
            bfr[3] = *(const bf16x8*)&Xl[swz64(ptOff3 + l16, kk * 4 + quad)];         \
            _Pragma("unroll")                                                         \
            for (int tt = 0; tt < 3; ++tt) {                                          \
                bf16x8 afr = *(const bf16x8*)&Wl[swz64(woch + tt*16 + l16, kk*4 + quad)]; \
                _Pragma("unroll")                                                     \
                for (int pt = 0; pt < 4; ++pt)                                        \
                    acc[tt][pt] = __builtin_amdgcn_mfma_f32_16x16x32_bf16(afr, bfr[pt], acc[tt][pt], 0, 0, 0); \
            }                                                                         \
        }                                                                             \
        __syncthreads();                                                              \
    }

    K1_CHUNK(0, fvA, fvB)
    K1_CHUNK(1, fvB, fvA)
    K1_CHUNK(2, fvA, fvB)
    K1_CHUNK(3, fvB, fvA)
#undef K1_CHUNK

    #pragma unroll
    for (int tt = 0; tt < 3; ++tt) {
        #pragma unroll
        for (int r = 0; r < 4; ++r) {
            int j = woch + tt * 16 + quad * 4 + r;    // oc 0..191
            float al = alB[j], be = beB[j];
            float y[4];
            y[0] = fmaxf(acc[tt][0][r] * al + be, 0.f);
            y[1] = fmaxf(acc[tt][1][r] * al + be, 0.f);
            y[2] = fmaxf(acc[tt][2][r] * al + be, 0.f);
            y[3] = fmaxf(acc[tt][3][r] * al + be, 0.f);
            if (j >= 32 && j < 64) {        // g: store TRANSPOSED [m][k]
                size_t mb = (size_t)bz * 4096 + pBase;
                int kk = j - 32;
                gbufT[(mb + ptOff0 + l16) * 32 + kk] = f2bs(y[0]);
                gbufT[(mb + ptOff1 + l16) * 32 + kk] = f2bs(y[1]);
                gbufT[(mb + ptOff2 + l16) * 32 + kk] = f2bs(y[2]);
                gbufT[(mb + ptOff3 + l16) * 32 + kk] = f2bs(y[3]);
            } else {                        // f / hh: 2x2 maxpool
                #pragma unroll
                for (int c = 0; c < 2; ++c) {
                    float v  = fmaxf(y[c], y[c + 2]);
                    float po = fmaxf(v, __shfl_xor(v, 1));
                    if ((l16 & 1) == 0) {
                        int col = wcol + c * 16 + l16;
                        int n = ptile * 32 + (col >> 1);
                        if (j < 32) fbufT[((size_t)bz * 1024 + n) * 32 + j] = f2bs(po);  // [n][k]
                        else        hhbuf[((size_t)bz * 128 + (j - 64)) * HW4 + n] = f2bs(po);
                    }
                }
            }
        }
    }
}

// ---------------------------------------------------------------------------
// Kernel 2: fused attention (constant-shift softmax) + conv4 + BN + residual.
// UNCHANGED from the passing round-3 version.
// ---------------------------------------------------------------------------
__global__ __launch_bounds__(256, 2) void attn_conv4(
    const short* __restrict__ gbufT,
    const short* __restrict__ fbufT,
    const short* __restrict__ hhbuf,
    const float* __restrict__ x,
    const short* __restrict__ w4T, const float* __restrict__ b4, const float* __restrict__ s4,
    const float* __restrict__ t4, const float* __restrict__ m4, const float* __restrict__ v4,
    const float* __restrict__ gamma, float* __restrict__ out)
{
    __shared__ __align__(16) short smem[24576];    // 48 KB
    __shared__ float alB4[256], beB4[256];
    __shared__ float Zl[64];
    short* sT0  = smem;            // [64m][64n] swz64 beta^T, 4096 sh (dbuf A)
    short* sT1  = smem + 4096;     //                          (dbuf B)
    short* hhl0 = smem + 8192;     // [128c][64n] swz64, 8192 sh (dbuf A)
    short* hhl1 = smem + 16384;    //                           (dbuf B)
    short* o_l  = smem;            // phase2: [64m][128c] swz128, 8192 sh
    short* Wl4  = smem + 8192;     // phase2: [256oc][32k] p40, 10240 sh

    const int t = threadIdx.x;
    const int lane = t & 63, wv = t >> 6;
    const int quad = lane >> 4, l16 = lane & 15;
    const int bz = blockIdx.y;
    const int m0 = blockIdx.x * 64;
    const f32x4 fzero = {0.f, 0.f, 0.f, 0.f};

    {   // conv4 BN constants
        float al = s4[t] * rsqrtf(v4[t] + EPS);
        alB4[t] = al; beB4[t] = (b4[t] - m4[t]) * al + t4[t];
    }

    const short* fT = fbufT + (size_t)bz * 1024 * 32;
    const short* hB = hhbuf + (size_t)bz * 128 * HW4;
    const int hrow = t >> 3, hnc = t & 7;

    // loop-invariant B-frag for s-phase: g^T[m0 + wv*16 + l16][quad*8..]
    bf16x8 bg = *(const bf16x8*)&gbufT[((size_t)bz * 4096 + m0 + wv * 16 + l16) * 32 + quad * 8];

    // prologue prefetch: tile 0 f-frags + hh tile in registers
    bf16x8 fr[4], hr[4];
    #pragma unroll
    for (int nt = 0; nt < 4; ++nt)
        fr[nt] = *(const bf16x8*)&fT[(nt * 16 + l16) * 32 + quad * 8];
    #pragma unroll
    for (int i = 0; i < 4; ++i)
        hr[i] = *(const bf16x8*)(hB + (size_t)(i * 32 + hrow) * HW4 + hnc * 8);

    float psum = 0.f;
    f32x4 oacc[2][4];              // [c-tile within slice][m-tile]
    #pragma unroll
    for (int a = 0; a < 2; ++a)
        #pragma unroll
        for (int b = 0; b < 4; ++b) oacc[a][b] = fzero;

    #pragma unroll 2
    for (int it = 0; it < 16; ++it) {
        const int n0n = ((it + 1) & 15) << 6;     // next tile (wraps; wrap loads dead)
        short* hb = (it & 1) ? hhl1 : hhl0;
        short* sT = (it & 1) ? sT1  : sT0;

        // commit current hh tile; issue next tile's loads
        #pragma unroll
        for (int i = 0; i < 4; ++i)
            *(bf16x8*)&hb[swz64(i * 32 + hrow, hnc)] = hr[i];
        #pragma unroll
        for (int i = 0; i < 4; ++i)
            hr[i] = *(const bf16x8*)(hB + (size_t)(i * 32 + hrow) * HW4 + n0n + hnc * 8);

        // s-phase: strip wv, all 64 n of this tile
        f32x4 sacc[4];
        #pragma unroll
        for (int nt = 0; nt < 4; ++nt)
            sacc[nt] = __builtin_amdgcn_mfma_f32_16x16x32_bf16(fr[nt], bg, fzero, 0, 0, 0);
        #pragma unroll
        for (int nt = 0; nt < 4; ++nt)
            fr[nt] = *(const bf16x8*)&fT[(n0n + nt * 16 + l16) * 32 + quad * 8];

        // exp(s - C), per-lane partial sum over n; store beta^T slice
        #pragma unroll
        for (int nt = 0; nt < 4; ++nt) {
            short4 ev;
            #pragma unroll
            for (int r = 0; r < 4; ++r) {
                float e = __expf(sacc[nt][r] - SM_SHIFT);
                psum += e;
                ((short*)&ev)[r] = f2bs(e);
            }
            *(short4*)&sT[swz64(wv * 16 + l16, nt * 2 + (quad >> 1)) + (quad & 1) * 4] = ev;
        }

        __syncthreads();   // hh + beta of this tile visible; prior-iter readers done

        // o-phase: c-slice [wv*32, wv*32+32), all 64 m
        #pragma unroll
        for (int kk = 0; kk < 2; ++kk) {
            bf16x8 ah0 = *(const bf16x8*)&hb[swz64(wv * 32 + l16,      kk * 4 + quad)];
            bf16x8 ah1 = *(const bf16x8*)&hb[swz64(wv * 32 + 16 + l16, kk * 4 + quad)];
            bf16x8 bs[4];
            #pragma unroll
            for (int mt = 0; mt < 4; ++mt)
                bs[mt] = *(const bf16x8*)&sT[swz64(mt * 16 + l16, kk * 4 + quad)];
            #pragma unroll
            for (int mt = 0; mt < 4; ++mt) {
                oacc[0][mt] = __builtin_amdgcn_mfma_f32_16x16x32_bf16(ah0, bs[mt], oacc[0][mt], 0, 0, 0);
                oacc[1][mt] = __builtin_amdgcn_mfma_f32_16x16x32_bf16(ah1, bs[mt], oacc[1][mt], 0, 0, 0);
            }
        }
    }

    // Z per m (wave's s-phase strip): reduce psum across quads, publish
    psum += __shfl_xor(psum, 16);
    psum += __shfl_xor(psum, 32);
    if (quad == 0) Zl[wv * 16 + l16] = psum;
    __syncthreads();   // all attn LDS reads complete + Zl visible

    // normalize + write o_l (bf16, swz128 [m][c]); wave covers its c-slice, all m
    #pragma unroll
    for (int mt = 0; mt < 4; ++mt) {
        float iv = 1.0f / Zl[mt * 16 + l16];
        #pragma unroll
        for (int ct2 = 0; ct2 < 2; ++ct2) {
            short4 ov;
            #pragma unroll
            for (int r = 0; r < 4; ++r) ((short*)&ov)[r] = f2bs(oacc[ct2][mt][r] * iv);
            *(short4*)&o_l[swz128(mt * 16 + l16, wv * 4 + ct2 * 2 + (quad >> 1)) + (quad & 1) * 4] = ov;
        }
    }

    // conv4: out[oc][m] = W4(256x128) . o(128x64m); W4 pre-converted bf16,
    // staged per 32-k chunk with register prefetch.
    f32x4 acc4[4][4];
    #pragma unroll
    for (int i = 0; i < 4; ++i)
        #pragma unroll
        for (int j = 0; j < 4; ++j) acc4[i][j] = fzero;

    const int wrow = t >> 2, wcid = t & 3;
    bf16x8 Wr[4];
    #pragma unroll
    for (int g = 0; g < 4; ++g)
        Wr[g] = *(const bf16x8*)(w4T + (g * 64 + wrow) * 128 + wcid * 8);

    #pragma unroll
    for (int k0i = 0; k0i < 4; ++k0i) {
        const int k0 = k0i * 32;
        __syncthreads();   // o_l writes visible (first iter); prior Wl4 readers done
        #pragma unroll
        for (int g = 0; g < 4; ++g)
            *(bf16x8*)&Wl4[p40(g * 64 + wrow, wcid)] = Wr[g];
        if (k0i < 3) {
            #pragma unroll
            for (int g = 0; g < 4; ++g)
                Wr[g] = *(const bf16x8*)(w4T + (g * 64 + wrow) * 128 + k0 + 32 + wcid * 8);
        }
        __syncthreads();
        bf16x8 bfr[4];
        #pragma unroll
        for (int mt = 0; mt < 4; ++mt)
            bfr[mt] = *(const bf16x8*)&o_l[swz128(mt * 16 + l16, (k0 >> 3) + quad)];
        #pragma unroll
        for (int ot = 0; ot < 4; ++ot) {
            bf16x8 afr = *(const bf16x8*)&Wl4[p40(wv * 64 + ot * 16 + l16, quad)];
            #pragma unroll
            for (int mt = 0; mt < 4; ++mt)
                acc4[ot][mt] = __builtin_amdgcn_mfma_f32_16x16x32_bf16(afr, bfr[mt], acc4[ot][mt], 0, 0, 0);
        }
    }

    float gm = gamma[0];
    #pragma unroll
    for (int ot = 0; ot < 4; ++ot) {
        #pragma unroll
        for (int r = 0; r < 4; ++r) {
            int oc = wv * 64 + ot * 16 + quad * 4 + r;
            float al = alB4[oc], be = beB4[oc];
            #pragma unroll
            for (int mt = 0; mt < 4; ++mt) {
                int p = m0 + mt * 16 + l16;
                float y  = acc4[ot][mt][r] * al + be;
                float xo = x[((size_t)bz * 256 + oc) * HW + p];
                out[((size_t)bz * 256 + oc) * HW + p] = gm * y + xo;
            }
        }
    }
}

extern "C" void kernel_launch(void* const* d_in, const int* in_sizes, int n_in,
                              void* d_out, int out_size, void* d_ws, size_t ws_size,
                              hipStream_t stream)
{
    const float* x  = (const float*)d_in[0];
    const float* w1 = (const float*)d_in[1];
    const float* b1 = (const float*)d_in[2];
    const float* s1 = (const float*)d_in[3];
    const float* t1 = (const float*)d_in[4];
    const float* m1 = (const float*)d_in[5];
    const float* v1 = (const float*)d_in[6];
    const float* w2 = (const float*)d_in[7];
    const float* b2 = (const float*)d_in[8];
    const float* s2 = (const float*)d_in[9];
    const float* t2 = (const float*)d_in[10];
    const float* m2 = (const float*)d_in[11];
    const float* v2 = (const float*)d_in[12];
    const float* w3 = (const float*)d_in[13];
    const float* b3 = (const float*)d_in[14];
    const float* s3 = (const float*)d_in[15];
    const float* t3 = (const float*)d_in[16];
    const float* m3 = (const float*)d_in[17];
    const float* v3 = (const float*)d_in[18];
    const float* w4 = (const float*)d_in[19];
    const float* b4 = (const float*)d_in[20];
    const float* s4 = (const float*)d_in[21];
    const float* t4 = (const float*)d_in[22];
    const float* m4 = (const float*)d_in[23];
    const float* v4 = (const float*)d_in[24];
    const float* gm = (const float*)d_in[25];
    float* out = (float*)d_out;

    short* gbufT = (short*)d_ws;                     // 8*4096*32 bf16 (2 MB, [m][k])
    short* fbufT = gbufT + (size_t)8 * 4096 * 32;    // 8*1024*32  (0.5 MB, [n][k])
    short* hhbuf = fbufT + (size_t)8 * 1024 * 32;    // 8*128*1024 (2 MB)
    short* w4T   = hhbuf + (size_t)8 * 128 * 1024;   // 256*128 bf16 (64 KB)

    conv123pool<<<dim3(32, 8), 512, 0, stream>>>(
        x, w1, b1, s1, t1, m1, v1, w2, b2, s2, t2, m2, v2, w3, b3, s3, t3, m3, v3,
        w4, w4T, gbufT, fbufT, hhbuf);
    attn_conv4<<<dim3(64, 8), 256, 0, stream>>>(
        gbufT, fbufT, hhbuf, x, w4T, b4, s4, t4, m4, v4, gm, out);
}